// Round 9
// baseline (5932.830 us; speedup 1.0000x reference)
//
#include <hip/hip_runtime.h>

// EagerRNN: B=64, T=512, F=512, H=1024.
// xproj = x @ W[:512] + b  (32768x1024x512 GEMM)
// scan:  state = tanh(xproj[:,t,:] + state @ W[512:])   512 sequential steps
// out: final state (64,1024) f32.
//
// Phase 2: persistent 64-block kernel, 4 groups x 16 slices, WAVE-AUTONOMOUS.
// Exchange = r7's proven self-validating 8B words (stolen LSB tag =
// (t>>1)&1; k_init pre-tags parity-1 so init zeros can't validate at t=1).
// Each wave loads its MFMA A-fragments DIRECTLY from the plain row-major
// global image (r5's HW-verified mapping: row=lane15, frag kk at
// row*2048 + kk*64 + sub*16) through a rolling 8-kk window interleaved
// with the MFMA chain: earliest-arrived producer chunks multiply while
// later ones are in flight. NO __syncthreads in the loop, no LDS state
// tile, no block-level jitter coupling, no drains, no flags.
// Register discipline (r5 lesson): window of 8 kk (16 u64) + breg[8] +
// acc[4] ~ 130 VGPR, all array indices compile-time static.
// Safety (wave-level induction, r5+r7): a wave's tagged store of t+1
// depends (via MFMA dataflow) on ALL its reads of t, so tag-t observed =>
// producer finished reading t-1; slot content is {t-2, t}; tag splits them.

typedef _Float16 f16;
typedef _Float16 f16x8 __attribute__((ext_vector_type(8)));
typedef _Float16 f16x4 __attribute__((ext_vector_type(4)));
typedef float f32x4 __attribute__((ext_vector_type(4)));
typedef unsigned long long u64;
typedef unsigned u32;
typedef unsigned long long u64x2 __attribute__((ext_vector_type(2)));

#define B_  64
#define T_  512
#define F_  512
#define H_  1024

// workspace layout (bytes)
#define XPH_OFF  0ull                         // f16 [T][B][H]  = 64 MB
#define WXT_OFF  67108864ull                  // f16 [H][F]     = 1 MB
#define WHT_OFF  68157440ull                  // f16 [H][H]     = 2 MB
#define SBUF_OFF 70254592ull                  // f16 image, 2 parities x 4 groups x 32768 B
#define WS_NEED  70516736ull

#define ALD64(p)    __hip_atomic_load((const u64*)(p), __ATOMIC_RELAXED, __HIP_MEMORY_SCOPE_AGENT)
#define AST64(p, v) __hip_atomic_store((u64*)(p), (v), __ATOMIC_RELAXED, __HIP_MEMORY_SCOPE_AGENT)

// 3-op tanh: e = e^{2x} via v_exp_f32(2x*log2e); tanh = 1 - 2/(e+1).
// Saturates correctly at +-1; error ~1e-6 << f16 quantization (r8-proven).
__device__ __forceinline__ float fast_tanh(float x) {
  float e;
  asm("v_exp_f32 %0, %1" : "=v"(e) : "v"(x * 2.885390081777927f));
  float r;
  asm("v_rcp_f32 %0, %1" : "=v"(r) : "v"(e + 1.0f));
  return 1.0f - 2.0f * r;
}

// ---------------------------------------------------------------------------
// init: parity-0 image words = 0 (state0 = 0, tag 0), parity-1 words = 1
// (tag 1 -> cannot falsely validate at t=1, where want = 0).  [r6 lesson]
__global__ __launch_bounds__(256) void k_init(u64* __restrict__ sbuf) {
  const unsigned i = blockIdx.x * 256 + threadIdx.x;   // 0..32767
  sbuf[i] = (i >= 16384) ? 1ull : 0ull;                // 16384 u64 per parity
}

// ---------------------------------------------------------------------------
// prep: W f32 [1536][1024] -> WxT f16 [h][k<512], WhT f16 [h][k<1024]
__global__ __launch_bounds__(256) void k_prep(const float* __restrict__ W,
                                              f16* __restrict__ WxT,
                                              f16* __restrict__ WhT) {
  __shared__ float tile[32][33];
  const int tid = threadIdx.x;
  const int kt = blockIdx.x >> 5;   // 0..47 (32 k-rows each)
  const int ht = blockIdx.x & 31;   // 0..31 (32 h-cols each)
#pragma unroll
  for (int p = 0; p < 4; ++p) {
    int kr = p * 8 + (tid >> 5);
    tile[kr][tid & 31] = W[(size_t)(kt * 32 + kr) * 1024 + ht * 32 + (tid & 31)];
  }
  __syncthreads();
  const int hl = tid >> 3;   // 0..31
  const int kq = tid & 7;    // 0..7  -> 4 k each
  f16x4 v;
#pragma unroll
  for (int j = 0; j < 4; ++j) v[j] = (f16)tile[kq * 4 + j][hl];
  const int h = ht * 32 + hl;
  const int kg = kt * 32 + kq * 4;
  if (kg < 512) *(f16x4*)(WxT + (size_t)h * 512 + kg) = v;
  else          *(f16x4*)(WhT + (size_t)h * 1024 + (kg - 512)) = v;
}

// ---------------------------------------------------------------------------
// phase 1: xph[t*64+b][h] = f16( x[b][t][:] @ Wx[:][h] + bias[h] )
__global__ __launch_bounds__(256) void k_xproj(const float* __restrict__ x,
                                               const f16* __restrict__ WxT,
                                               const float* __restrict__ bias,
                                               f16* __restrict__ xph) {
  __shared__ __align__(16) unsigned char Al[65536];  // [64 m][512 k] f16, swizzled
  __shared__ __align__(16) unsigned char Bl[65536];  // [64 n][512 k] f16, swizzled
  const int tid = threadIdx.x;
  const int l = tid & 63, w = tid >> 6;
  const int lane15 = l & 15, sub = l >> 4;
  const int m0 = blockIdx.x * 64;
  const int bidx = m0 >> 9;     // batch
  const int t0 = m0 & 511;      // time base

  {
    const int r = tid >> 2, qq = tid & 3;
    const float* xs = x + (size_t)(m0 + r) * 512;
#pragma unroll
    for (int i = 0; i < 16; ++i) {
      int s = qq * 16 + i;          // 16B slot 0..63
      int c = s ^ (r & 7);          // source k-chunk (swizzle on source)
      const float4 f0 = *(const float4*)(xs + c * 8);
      const float4 f1 = *(const float4*)(xs + c * 8 + 4);
      f16x8 v;
      v[0] = (f16)f0.x; v[1] = (f16)f0.y; v[2] = (f16)f0.z; v[3] = (f16)f0.w;
      v[4] = (f16)f1.x; v[5] = (f16)f1.y; v[6] = (f16)f1.z; v[7] = (f16)f1.w;
      *(f16x8*)(Al + r * 1024 + s * 16) = v;
    }
  }

  const int mh = (w >> 1) * 32, nh = (w & 1) * 32;
  const int rA0 = mh + lane15, rA1 = mh + 16 + lane15;
  const int rB0 = nh + lane15, rB1 = nh + 16 + lane15;

  for (int nb = 0; nb < 16; ++nb) {
    const int n0 = nb * 64;
    __syncthreads();   // Bl safe to overwrite
    {
      const int r = tid >> 2, qq = tid & 3;
      const f16* bs = WxT + (size_t)(n0 + r) * 512;
#pragma unroll
      for (int i = 0; i < 16; ++i) {
        int s = qq * 16 + i;
        int c = s ^ (r & 7);
        f16x8 v = *(const f16x8*)(bs + c * 8);
        *(f16x8*)(Bl + r * 1024 + s * 16) = v;
      }
    }
    __syncthreads();
    f32x4 acc00 = {0.f,0.f,0.f,0.f}, acc01 = {0.f,0.f,0.f,0.f};
    f32x4 acc10 = {0.f,0.f,0.f,0.f}, acc11 = {0.f,0.f,0.f,0.f};
#pragma unroll
    for (int kk = 0; kk < 16; ++kk) {
      const int s = kk * 4 + sub;
      f16x8 a0 = *(const f16x8*)(Al + rA0 * 1024 + ((s ^ (rA0 & 7)) << 4));
      f16x8 a1 = *(const f16x8*)(Al + rA1 * 1024 + ((s ^ (rA1 & 7)) << 4));
      f16x8 b0 = *(const f16x8*)(Bl + rB0 * 1024 + ((s ^ (rB0 & 7)) << 4));
      f16x8 b1 = *(const f16x8*)(Bl + rB1 * 1024 + ((s ^ (rB1 & 7)) << 4));
      acc00 = __builtin_amdgcn_mfma_f32_16x16x32_f16(a0, b0, acc00, 0, 0, 0);
      acc01 = __builtin_amdgcn_mfma_f32_16x16x32_f16(a0, b1, acc01, 0, 0, 0);
      acc10 = __builtin_amdgcn_mfma_f32_16x16x32_f16(a1, b0, acc10, 0, 0, 0);
      acc11 = __builtin_amdgcn_mfma_f32_16x16x32_f16(a1, b1, acc11, 0, 0, 0);
    }
    const float bv0 = bias[n0 + nh + lane15];
    const float bv1 = bias[n0 + nh + 16 + lane15];
#pragma unroll
    for (int j = 0; j < 4; ++j) {
      const int r0 = mh + sub * 4 + j;
      const int r1 = mh + 16 + sub * 4 + j;
      const size_t row0 = (size_t)(t0 + r0) * 64 + bidx;
      const size_t row1 = (size_t)(t0 + r1) * 64 + bidx;
      xph[row0 * 1024 + n0 + nh + lane15]      = (f16)(acc00[j] + bv0);
      xph[row0 * 1024 + n0 + nh + 16 + lane15] = (f16)(acc01[j] + bv1);
      xph[row1 * 1024 + n0 + nh + lane15]      = (f16)(acc10[j] + bv0);
      xph[row1 * 1024 + n0 + nh + 16 + lane15] = (f16)(acc11[j] + bv1);
    }
  }
}

// ---------------------------------------------------------------------------
// phase 2: persistent recurrence, wave-autonomous rolling consumption.
// 64 blocks = 4 groups x 16 slices. LDS: WhL 96KB (kk 8..31) + tbuf 2.2KB.
// Image per group per parity: plain row-major f16 [16][1024] (2048B rows).
__global__ __launch_bounds__(256, 1) void k_rnn(const f16* __restrict__ xph,
                                                const f16* __restrict__ WhT,
                                                f16* sbuf,
                                                float* __restrict__ out) {
  __shared__ __align__(16) unsigned char lds[98304 + 2176];
  unsigned char* WhL  = lds;            // 64 rows x 1536 B (kslot 32..127)
  unsigned char* tbuf = lds + 98304;    // 16 rows x 136 B (wave-local)
  const int tid = threadIdx.x;
  const int l = tid & 63, w = tid >> 6;          // w = n-tile 0..3
  const int lane15 = l & 15, sub = l >> 4;
  const int bid = blockIdx.x;
  const int group = bid & 3;
  const int slice = bid >> 2;                    // 0..15

  // Wh slice -> LDS (rows r=0..63 <-> h = slice*64+r), swizzled 16B slots
  for (int i = 0; i < 24; ++i) {
    int s = i * 256 + tid;          // 0..6143
    int r = s / 96;
    int ks = 32 + (s - r * 96);     // kslot 32..127
    f16x8 v = *(const f16x8*)(WhT + (size_t)(slice * 64 + r) * 1024 + ks * 8);
    *(f16x8*)(WhL + r * 1536 + ((ks ^ (r & 7)) - 32) * 16) = v;
  }
  // kk = 0..7 B-fragments in registers (stationary all 512 steps)
  const int colL = slice * 64 + w * 16 + lane15; // this lane's output column
  f16x8 breg[8];
  {
    const f16* src = WhT + (size_t)colL * 1024 + sub * 8;
#pragma unroll
    for (int kk = 0; kk < 8; ++kk) breg[kk] = *(const f16x8*)(src + kk * 32);
  }
#pragma unroll
  for (int kk = 0; kk < 8; ++kk) asm volatile("" : "+v"(breg[kk]));
  __syncthreads();   // WhL ready (only barrier in the kernel)

  const int rB = w * 16 + lane15, xB = rB & 7;
  const unsigned char* whb = WhL + rB * 1536;

  // per-lane A-fragment base: row = lane15, k-phase = sub (r5 HW-verified)
  const int fragoff = lane15 * 2048 + sub * 16;
  // producer store position: row = lane15, 4 cols at c0 (8B packed + tag)
  const int c0 = slice * 64 + w * 16 + sub * 4;
  const int stoff = lane15 * 2048 + c0 * 2;
  const size_t gbase = (size_t)group * 32768;

  for (int t = 0; t < T_; ++t) {
    const char* ib = (const char*)sbuf + (size_t)(t & 1) * 131072 + gbase;
    char*       ob = (char*)sbuf + (size_t)((t + 1) & 1) * 131072 + gbase;

    // xp for this step (plain cached loads, issued first)
    float xpv[4];
#pragma unroll
    for (int j = 0; j < 4; ++j)
      xpv[j] = (float)xph[(size_t)(t * 64 + group * 16 + sub * 4 + j) * 1024 + colL];

    const char* rb = ib + fragoff;
    const u32 want = (u32)((t >> 1) & 1);

    // rolling 8-kk window: issue, then per-kk {validate-spin, MFMA, refill}
    u64 lo[8], hi[8];
#pragma unroll
    for (int i = 0; i < 8; ++i) {
      lo[i] = ALD64(rb + i * 64);
      hi[i] = ALD64(rb + i * 64 + 8);
    }
    f32x4 acc[4];
#pragma unroll
    for (int i = 0; i < 4; ++i) acc[i] = (f32x4){0.f, 0.f, 0.f, 0.f};

#pragma unroll
    for (int kk = 0; kk < 32; ++kk) {
      u64 L = lo[kk & 7], H = hi[kk & 7];
      // wave-collective tag spin: both 8B words must carry epoch tag
      while (__any((int)((((u32)L ^ want) | ((u32)H ^ want)) & 1u))) {
        L = ALD64(rb + kk * 64);
        H = ALD64(rb + kk * 64 + 8);
      }
      if (kk < 24) {                          // refill window slot
        lo[kk & 7] = ALD64(rb + (kk + 8) * 64);
        hi[kk & 7] = ALD64(rb + (kk + 8) * 64 + 8);
      }
      u64x2 pk; pk[0] = L; pk[1] = H;
      f16x8 a = __builtin_bit_cast(f16x8, pk);
      const int s = kk * 4 + sub;
      f16x8 b = (kk < 8) ? breg[kk]
                         : *(const f16x8*)(whb + (((s ^ xB) - 32) << 4));
      acc[kk & 3] = __builtin_amdgcn_mfma_f32_16x16x32_f16(a, b, acc[kk & 3], 0, 0, 0);
    }
    float rv[4];
#pragma unroll
    for (int j = 0; j < 4; ++j)
      rv[j] = acc[0][j] + acc[1][j] + acc[2][j] + acc[3][j] + xpv[j];

    if (t == T_ - 1) {
#pragma unroll
      for (int j = 0; j < 4; ++j)
        out[(size_t)(group * 16 + sub * 4 + j) * 1024 + colL] = fast_tanh(rv[j]);
      break;
    }

    // wave-local transpose (disjoint bytes per wave; same-wave write->read
    // ordered by lgkmcnt), then one tagged fire-and-forget 8B store
#pragma unroll
    for (int j = 0; j < 4; ++j) {
      f16 hv = (f16)fast_tanh(rv[j]);
      *(f16*)(tbuf + (sub * 4 + j) * 136 + (w * 16 + lane15) * 2) = hv;
    }
    asm volatile("s_waitcnt lgkmcnt(0)" ::: "memory");
    {
      u64 packed = *(const u64*)(tbuf + lane15 * 136 + (w * 16 + sub * 4) * 2);
      packed = (packed & ~1ull) | (u64)(((t + 1) >> 1) & 1);
      AST64(ob + stoff, packed);   // no drain, no flag, no barrier
    }
  }
}

// ---------------------------------------------------------------------------
extern "C" void kernel_launch(void* const* d_in, const int* in_sizes, int n_in,
                              void* d_out, int out_size, void* d_ws, size_t ws_size,
                              hipStream_t stream) {
  const float* x    = (const float*)d_in[0];
  const float* W    = (const float*)d_in[1];
  const float* bias = (const float*)d_in[2];
  float* out = (float*)d_out;
  char* w = (char*)d_ws;

  f16* xph = (f16*)(w + XPH_OFF);
  f16* WxT = (f16*)(w + WXT_OFF);
  f16* WhT = (f16*)(w + WHT_OFF);
  f16* sbuf = (f16*)(w + SBUF_OFF);

  // tag-aware image init: parity 0 = state0 (tag 0), parity 1 = tag 1
  k_init<<<dim3(128), dim3(256), 0, stream>>>((u64*)(w + SBUF_OFF));

  k_prep<<<dim3(48 * 32), dim3(256), 0, stream>>>(W, WxT, WhT);
  k_xproj<<<dim3(512), dim3(256), 0, stream>>>(x, WxT, bias, xph);
  k_rnn<<<dim3(64), dim3(256), 0, stream>>>(xph, WhT, sbuf, out);
}

// Round 10
// 1866.662 us; speedup vs baseline: 3.1783x; 3.1783x over previous
//
#include <hip/hip_runtime.h>

// EagerRNN: B=64, T=512, F=512, H=1024.
// xproj = x @ W[:512] + b  (32768x1024x512 GEMM)
// scan:  state = tanh(xproj[:,t,:] + state @ W[512:])   512 sequential steps
// out: final state (64,1024) f32.
//
// Phase 2: persistent 64-block kernel (r7's proven protocol: self-validating
// 8B words, stolen LSB tag = (t>>1)&1, fire-and-forget stores, no flags,
// k_init pre-tags parity-1). This round shaves on-chain latency terms:
//  - dual-sample pipelined tag polling (two in-flight 16-word sets ->
//    detection quantum ~halved, barrier jitter-max shrunk)
//  - double-buffered stL -> ONE __syncthreads per step (was two)
//  - acc[4] interleaved MFMA chains (8-deep dependency, was 16)
//  - fast_tanh (3-op exp/rcp, r8-proven numerics)
// Measured model: period = RT(~2.45us, fabric store->visible->load) +
// C(~0.65us on-chain compute) + detect quantization. RT untouchable from
// HIP (r4 sc0 experiment hung; agent scope = MALL). This attacks C+detect.

typedef _Float16 f16;
typedef _Float16 f16x8 __attribute__((ext_vector_type(8)));
typedef _Float16 f16x4 __attribute__((ext_vector_type(4)));
typedef float f32x4 __attribute__((ext_vector_type(4)));
typedef unsigned long long u64;
typedef unsigned u32;

#define B_  64
#define T_  512
#define F_  512
#define H_  1024

// workspace layout (bytes)
#define XPH_OFF  0ull                         // f16 [T][B][H]  = 64 MB
#define WXT_OFF  67108864ull                  // f16 [H][F]     = 1 MB
#define WHT_OFF  68157440ull                  // f16 [H][H]     = 2 MB
#define SBUF_OFF 70254592ull                  // f16 image, 2 parities x 4 groups x 32768 B
#define WS_NEED  70516736ull

#define ALD64(p)    __hip_atomic_load((const u64*)(p), __ATOMIC_RELAXED, __HIP_MEMORY_SCOPE_AGENT)
#define AST64(p, v) __hip_atomic_store((u64*)(p), (v), __ATOMIC_RELAXED, __HIP_MEMORY_SCOPE_AGENT)

// 3-op tanh: e = e^{2x} via v_exp_f32(2x*log2e); tanh = 1 - 2/(e+1).
// Saturates correctly at +-1; error ~1e-6 << f16 quantization (r8-proven).
__device__ __forceinline__ float fast_tanh(float x) {
  float e;
  asm("v_exp_f32 %0, %1" : "=v"(e) : "v"(x * 2.885390081777927f));
  float r;
  asm("v_rcp_f32 %0, %1" : "=v"(r) : "v"(e + 1.0f));
  return 1.0f - 2.0f * r;
}

// ---------------------------------------------------------------------------
// init: parity-0 image words = 0 (state0 = 0, tag 0), parity-1 words = 1
// (tag 1 -> cannot falsely validate at t=1, where want = 0).  [r6 lesson]
__global__ __launch_bounds__(256) void k_init(u64* __restrict__ sbuf) {
  const unsigned i = blockIdx.x * 256 + threadIdx.x;   // 0..32767
  sbuf[i] = (i >= 16384) ? 1ull : 0ull;                // 16384 u64 per parity
}

// ---------------------------------------------------------------------------
// prep: W f32 [1536][1024] -> WxT f16 [h][k<512], WhT f16 [h][k<1024]
__global__ __launch_bounds__(256) void k_prep(const float* __restrict__ W,
                                              f16* __restrict__ WxT,
                                              f16* __restrict__ WhT) {
  __shared__ float tile[32][33];
  const int tid = threadIdx.x;
  const int kt = blockIdx.x >> 5;   // 0..47 (32 k-rows each)
  const int ht = blockIdx.x & 31;   // 0..31 (32 h-cols each)
#pragma unroll
  for (int p = 0; p < 4; ++p) {
    int kr = p * 8 + (tid >> 5);
    tile[kr][tid & 31] = W[(size_t)(kt * 32 + kr) * 1024 + ht * 32 + (tid & 31)];
  }
  __syncthreads();
  const int hl = tid >> 3;   // 0..31
  const int kq = tid & 7;    // 0..7  -> 4 k each
  f16x4 v;
#pragma unroll
  for (int j = 0; j < 4; ++j) v[j] = (f16)tile[kq * 4 + j][hl];
  const int h = ht * 32 + hl;
  const int kg = kt * 32 + kq * 4;
  if (kg < 512) *(f16x4*)(WxT + (size_t)h * 512 + kg) = v;
  else          *(f16x4*)(WhT + (size_t)h * 1024 + (kg - 512)) = v;
}

// ---------------------------------------------------------------------------
// phase 1: xph[t*64+b][h] = f16( x[b][t][:] @ Wx[:][h] + bias[h] )
__global__ __launch_bounds__(256) void k_xproj(const float* __restrict__ x,
                                               const f16* __restrict__ WxT,
                                               const float* __restrict__ bias,
                                               f16* __restrict__ xph) {
  __shared__ __align__(16) unsigned char Al[65536];  // [64 m][512 k] f16, swizzled
  __shared__ __align__(16) unsigned char Bl[65536];  // [64 n][512 k] f16, swizzled
  const int tid = threadIdx.x;
  const int l = tid & 63, w = tid >> 6;
  const int lane15 = l & 15, sub = l >> 4;
  const int m0 = blockIdx.x * 64;
  const int bidx = m0 >> 9;     // batch
  const int t0 = m0 & 511;      // time base

  {
    const int r = tid >> 2, qq = tid & 3;
    const float* xs = x + (size_t)(m0 + r) * 512;
#pragma unroll
    for (int i = 0; i < 16; ++i) {
      int s = qq * 16 + i;          // 16B slot 0..63
      int c = s ^ (r & 7);          // source k-chunk (swizzle on source)
      const float4 f0 = *(const float4*)(xs + c * 8);
      const float4 f1 = *(const float4*)(xs + c * 8 + 4);
      f16x8 v;
      v[0] = (f16)f0.x; v[1] = (f16)f0.y; v[2] = (f16)f0.z; v[3] = (f16)f0.w;
      v[4] = (f16)f1.x; v[5] = (f16)f1.y; v[6] = (f16)f1.z; v[7] = (f16)f1.w;
      *(f16x8*)(Al + r * 1024 + s * 16) = v;
    }
  }

  const int mh = (w >> 1) * 32, nh = (w & 1) * 32;
  const int rA0 = mh + lane15, rA1 = mh + 16 + lane15;
  const int rB0 = nh + lane15, rB1 = nh + 16 + lane15;

  for (int nb = 0; nb < 16; ++nb) {
    const int n0 = nb * 64;
    __syncthreads();   // Bl safe to overwrite
    {
      const int r = tid >> 2, qq = tid & 3;
      const f16* bs = WxT + (size_t)(n0 + r) * 512;
#pragma unroll
      for (int i = 0; i < 16; ++i) {
        int s = qq * 16 + i;
        int c = s ^ (r & 7);
        f16x8 v = *(const f16x8*)(bs + c * 8);
        *(f16x8*)(Bl + r * 1024 + s * 16) = v;
      }
    }
    __syncthreads();
    f32x4 acc00 = {0.f,0.f,0.f,0.f}, acc01 = {0.f,0.f,0.f,0.f};
    f32x4 acc10 = {0.f,0.f,0.f,0.f}, acc11 = {0.f,0.f,0.f,0.f};
#pragma unroll
    for (int kk = 0; kk < 16; ++kk) {
      const int s = kk * 4 + sub;
      f16x8 a0 = *(const f16x8*)(Al + rA0 * 1024 + ((s ^ (rA0 & 7)) << 4));
      f16x8 a1 = *(const f16x8*)(Al + rA1 * 1024 + ((s ^ (rA1 & 7)) << 4));
      f16x8 b0 = *(const f16x8*)(Bl + rB0 * 1024 + ((s ^ (rB0 & 7)) << 4));
      f16x8 b1 = *(const f16x8*)(Bl + rB1 * 1024 + ((s ^ (rB1 & 7)) << 4));
      acc00 = __builtin_amdgcn_mfma_f32_16x16x32_f16(a0, b0, acc00, 0, 0, 0);
      acc01 = __builtin_amdgcn_mfma_f32_16x16x32_f16(a0, b1, acc01, 0, 0, 0);
      acc10 = __builtin_amdgcn_mfma_f32_16x16x32_f16(a1, b0, acc10, 0, 0, 0);
      acc11 = __builtin_amdgcn_mfma_f32_16x16x32_f16(a1, b1, acc11, 0, 0, 0);
    }
    const float bv0 = bias[n0 + nh + lane15];
    const float bv1 = bias[n0 + nh + 16 + lane15];
#pragma unroll
    for (int j = 0; j < 4; ++j) {
      const int r0 = mh + sub * 4 + j;
      const int r1 = mh + 16 + sub * 4 + j;
      const size_t row0 = (size_t)(t0 + r0) * 64 + bidx;
      const size_t row1 = (size_t)(t0 + r1) * 64 + bidx;
      xph[row0 * 1024 + n0 + nh + lane15]      = (f16)(acc00[j] + bv0);
      xph[row0 * 1024 + n0 + nh + 16 + lane15] = (f16)(acc01[j] + bv1);
      xph[row1 * 1024 + n0 + nh + lane15]      = (f16)(acc10[j] + bv0);
      xph[row1 * 1024 + n0 + nh + 16 + lane15] = (f16)(acc11[j] + bv1);
    }
  }
}

// ---------------------------------------------------------------------------
// phase 2: persistent recurrence. 64 blocks = 4 groups (16 batch rows) x 16
// slices (64 H-cols). Wh slice: kk 0..9 in regs, kk 10..31 in LDS (88 KB);
// stL double-buffered by step parity (one barrier/step).
__global__ __launch_bounds__(256, 1) void k_rnn(const f16* __restrict__ xph,
                                                const f16* __restrict__ WhT,
                                                f16* sbuf,
                                                float* __restrict__ out) {
  __shared__ __align__(16) unsigned char lds[157824];
  unsigned char* WhL  = lds;             // 64 rows x 1408 B (kslot 40..127)
  unsigned char* stL0 = lds + 90112;     // 16 rows x 2048 B (parity 0)
  unsigned char* stL1 = lds + 122880;    // 16 rows x 2048 B (parity 1)
  unsigned char* tbuf = lds + 155648;    // 16 rows x 136 B  (wave transpose)
  const int tid = threadIdx.x;
  const int l = tid & 63, w = tid >> 6;          // w = n-tile 0..3
  const int lane15 = l & 15, sub = l >> 4;
  const int bid = blockIdx.x;
  const int group = (bid & 7) >> 1;              // 0..3 (XCD-pair colocated)
  const int slice = (bid >> 3) * 2 + (bid & 1);  // 0..15

  // Wh slice -> LDS (rows r=0..63 <-> h = slice*64+r), swizzled 16B slots.
  // kslot base 40 is 8-aligned so XOR with (r&7) stays in [40,127].
  for (int i = 0; i < 22; ++i) {
    int s = i * 256 + tid;          // 0..5631
    int r = s / 88;
    int ks = 40 + (s - r * 88);     // kslot 40..127
    f16x8 v = *(const f16x8*)(WhT + (size_t)(slice * 64 + r) * 1024 + ks * 8);
    *(f16x8*)(WhL + r * 1408 + ((ks ^ (r & 7)) - 40) * 16) = v;
  }
  // kk = 0..9 B-fragments in registers (stationary all 512 steps)
  const int colL = slice * 64 + w * 16 + lane15; // this lane's output column
  f16x8 breg[10];
  {
    const f16* src = WhT + (size_t)colL * 1024 + sub * 8;
#pragma unroll
    for (int kk = 0; kk < 10; ++kk) breg[kk] = *(const f16x8*)(src + kk * 32);
  }
#pragma unroll
  for (int kk = 0; kk < 10; ++kk) asm volatile("" : "+v"(breg[kk]));

  const int rA = lane15, xA = rA & 7;
  const int rB = w * 16 + lane15, xB = rB & 7;
  const unsigned char* whb = WhL + rB * 1408;

  // staging: thread (p = tid>>4, q = tid&15) owns producer p's 8B chunk q
  const int p = tid >> 4, q = tid & 15;
  const int cmt = p * 128 + q * 8;               // LDS commit offset
  // packed-store constants (4 f16 cols per thread, row = lane15), swizzled
  const int c0s = slice * 64 + w * 16 + sub * 4;
  const int stoff = lane15 * 2048 + (((c0s >> 3) ^ (lane15 & 7)) << 4) + (c0s & 7) * 2;

  for (int t = 0; t < T_; ++t) {
    const char* ib = (const char*)sbuf + (size_t)(t & 1) * 131072 + group * 32768;
    char*       ob = (char*)sbuf + (size_t)((t + 1) & 1) * 131072 + group * 32768;
    unsigned char* stC = (t & 1) ? stL1 : stL0;

    // xp for this step (plain cached loads, issued before the poll)
    float xpv[4];
#pragma unroll
    for (int j = 0; j < 4; ++j)
      xpv[j] = (float)xph[(size_t)(t * 64 + group * 16 + sub * 4 + j) * 1024 + colL];

    // ---- dual-sample pipelined tag polling: two in-flight 16-word sets ----
    {
      const char* src = ib + cmt;
      const u32 want = (u32)((t >> 1) & 1);
      u64 tA[16], tB[16];
#pragma unroll
      for (int i = 0; i < 16; ++i) tA[i] = ALD64(src + i * 2048);
#pragma unroll
      for (int i = 0; i < 16; ++i) tB[i] = ALD64(src + i * 2048);
      for (;;) {
        u32 bad = 0;
#pragma unroll
        for (int i = 0; i < 16; ++i) bad |= ((u32)tA[i] ^ want) & 1u;
        if (!bad) {
#pragma unroll
          for (int i = 0; i < 16; ++i) *(u64*)(stC + i * 2048 + cmt) = tA[i];
          break;
        }
#pragma unroll
        for (int i = 0; i < 16; ++i) tA[i] = ALD64(src + i * 2048);
        bad = 0;
#pragma unroll
        for (int i = 0; i < 16; ++i) bad |= ((u32)tB[i] ^ want) & 1u;
        if (!bad) {
#pragma unroll
          for (int i = 0; i < 16; ++i) *(u64*)(stC + i * 2048 + cmt) = tB[i];
          break;
        }
#pragma unroll
        for (int i = 0; i < 16; ++i) tB[i] = ALD64(src + i * 2048);
      }
    }
    __syncthreads();   // stC complete (the only barrier in the step)

    const unsigned char* stLb = stC + rA * 2048;
    f32x4 acc[4];
#pragma unroll
    for (int i = 0; i < 4; ++i) acc[i] = (f32x4){0.f, 0.f, 0.f, 0.f};
#pragma unroll
    for (int kk = 0; kk < 32; ++kk) {
      const int s = kk * 4 + sub;
      f16x8 a = *(const f16x8*)(stLb + ((s ^ xA) << 4));
      f16x8 b = (kk < 10) ? breg[kk]
                          : *(const f16x8*)(whb + (((s ^ xB) - 40) << 4));
      acc[kk & 3] = __builtin_amdgcn_mfma_f32_16x16x32_f16(a, b, acc[kk & 3], 0, 0, 0);
    }
    float rv[4];
#pragma unroll
    for (int j = 0; j < 4; ++j)
      rv[j] = acc[0][j] + acc[1][j] + acc[2][j] + acc[3][j] + xpv[j];

    if (t == T_ - 1) {
#pragma unroll
      for (int j = 0; j < 4; ++j)
        out[(size_t)(group * 16 + sub * 4 + j) * 1024 + colL] = fast_tanh(rv[j]);
      break;
    }

    // wave-local transpose (disjoint columns per wave; same-wave write->read
    // ordered by lgkmcnt), then one tagged fire-and-forget 8B store
#pragma unroll
    for (int j = 0; j < 4; ++j) {
      f16 hv = (f16)fast_tanh(rv[j]);
      *(f16*)(tbuf + (sub * 4 + j) * 136 + (w * 16 + lane15) * 2) = hv;
    }
    asm volatile("s_waitcnt lgkmcnt(0)" ::: "memory");
    {
      u64 packed = *(const u64*)(tbuf + lane15 * 136 + (w * 16 + sub * 4) * 2);
      // stolen tag bit: LSB of f16#0 <- ((t+1)>>1) & 1  (<=1 ulp on 1/4 elems)
      packed = (packed & ~1ull) | (u64)(((t + 1) >> 1) & 1);
      AST64(ob + stoff, packed);   // no drain, no flag
    }
  }
}

// ---------------------------------------------------------------------------
extern "C" void kernel_launch(void* const* d_in, const int* in_sizes, int n_in,
                              void* d_out, int out_size, void* d_ws, size_t ws_size,
                              hipStream_t stream) {
  const float* x    = (const float*)d_in[0];
  const float* W    = (const float*)d_in[1];
  const float* bias = (const float*)d_in[2];
  float* out = (float*)d_out;
  char* w = (char*)d_ws;

  f16* xph = (f16*)(w + XPH_OFF);
  f16* WxT = (f16*)(w + WXT_OFF);
  f16* WhT = (f16*)(w + WHT_OFF);
  f16* sbuf = (f16*)(w + SBUF_OFF);

  // tag-aware image init: parity 0 = state0 (tag 0), parity 1 = tag 1
  k_init<<<dim3(128), dim3(256), 0, stream>>>((u64*)(w + SBUF_OFF));

  k_prep<<<dim3(48 * 32), dim3(256), 0, stream>>>(W, WxT, WhT);
  k_xproj<<<dim3(512), dim3(256), 0, stream>>>(x, WxT, bias, xph);
  k_rnn<<<dim3(64), dim3(256), 0, stream>>>(xph, WhT, sbuf, out);
}